// Round 6
// baseline (22178.807 us; speedup 1.0000x reference)
//
#include <hip/hip_runtime.h>

#define H 2048
#define SEQ 4096
#define NOUT 1000
#define NBLK 64          // recurrence blocks
#define RPB 32           // rows per block
#define RPW 4            // rows per wave
#define THREADS_REC 512  // 8 waves

typedef unsigned long long ulong64;

// ---------------------------------------------------------------- init
// pbuf: 2 buffers x 2048 packets (lo=f32 value bits, hi=epoch).
// buf0 <- (h0, epoch 0); buf1 <- epoch -1 (never matches 1..4095).
__global__ void init_kernel(const float* __restrict__ h0, ulong64* __restrict__ pbuf) {
    int i = blockIdx.x * blockDim.x + threadIdx.x;
    if (i < H) {
        pbuf[i]     = (ulong64)__float_as_uint(h0[i]);   // epoch 0
        pbuf[H + i] = 0xFFFFFFFF00000000ULL;             // epoch -1
    }
}

__global__ void copy_hidden_kernel(const float* __restrict__ hidden, float* __restrict__ out) {
    int i = blockIdx.x * blockDim.x + threadIdx.x;
    if (i < H) out[i] = hidden[i];
}

// ------------------------------------------- GEMM  C = A * Bt^T + bias
#define TS 64
#define KK 16
#define LP 21
__global__ __launch_bounds__(256) void gemm_abt_f32(
    const float* __restrict__ A, const float* __restrict__ Bt,
    const float* __restrict__ bias, float* __restrict__ C,
    int M, int N, int K)
{
    __shared__ float As[TS][LP];
    __shared__ float Bs[TS][LP];
    const int tid = threadIdx.x;
    const int tx = tid & 15, ty = tid >> 4;
    const int bm = blockIdx.y * TS, bn = blockIdx.x * TS;
    const int lrow = tid >> 2;
    const int lcol = (tid & 3) << 2;
    float acc[4][4] = {};
    for (int k0 = 0; k0 < K; k0 += KK) {
        float4 av, bv;
        av = *(const float4*)(A + (size_t)(bm + lrow) * K + k0 + lcol);
        int brow = bn + lrow;
        if (brow < N) bv = *(const float4*)(Bt + (size_t)brow * K + k0 + lcol);
        else { bv.x = bv.y = bv.z = bv.w = 0.f; }
        __syncthreads();
        As[lrow][lcol+0] = av.x; As[lrow][lcol+1] = av.y;
        As[lrow][lcol+2] = av.z; As[lrow][lcol+3] = av.w;
        Bs[lrow][lcol+0] = bv.x; Bs[lrow][lcol+1] = bv.y;
        Bs[lrow][lcol+2] = bv.z; Bs[lrow][lcol+3] = bv.w;
        __syncthreads();
        #pragma unroll
        for (int k = 0; k < KK; ++k) {
            float ar[4], br[4];
            #pragma unroll
            for (int i = 0; i < 4; ++i) ar[i] = As[ty*4+i][k];
            #pragma unroll
            for (int j = 0; j < 4; ++j) br[j] = Bs[tx*4+j][k];
            #pragma unroll
            for (int i = 0; i < 4; ++i)
                #pragma unroll
                for (int j = 0; j < 4; ++j)
                    acc[i][j] = fmaf(ar[i], br[j], acc[i][j]);
        }
    }
    #pragma unroll
    for (int i = 0; i < 4; ++i) {
        int row = bm + ty*4 + i;
        #pragma unroll
        for (int j = 0; j < 4; ++j) {
            int col = bn + tx*4 + j;
            if (col < N) C[(size_t)row * N + col] = acc[i][j] + bias[col];
        }
    }
}

// ------------------------------------------------- persistent RNN scan
// 64 blocks x 512 threads, fully wave-autonomous (NO barriers, NO flags).
// h is exchanged as (value,epoch) 8-byte packets in a double buffer at the
// LLC; detection of step-t data IS the data fetch (poll the packets).
__global__ __launch_bounds__(THREADS_REC, 2) void rnn_scan_kernel(
    const float* __restrict__ xp, const float* __restrict__ Whh,
    const float* __restrict__ bhh,
    float* __restrict__ hs, ulong64* pbuf)
{
    const int tid  = threadIdx.x;
    const int lane = tid & 63;
    const int wid  = tid >> 6;
    const int bid  = blockIdx.x;
    const int rbase = bid * RPB + wid * RPW;

    // --- load weights into registers (one-time 16 MiB, coalesced) ---
    float w[RPW][32];
    #pragma unroll
    for (int r = 0; r < RPW; ++r) {
        const float* wp = Whh + (size_t)(rbase + r) * H + (lane << 2);
        #pragma unroll
        for (int k = 0; k < 8; ++k) {
            float4 wv = *(const float4*)(wp + (k << 8));
            w[r][k*4+0] = wv.x; w[r][k*4+1] = wv.y;
            w[r][k*4+2] = wv.z; w[r][k*4+3] = wv.w;
        }
    }
    #pragma unroll
    for (int r = 0; r < RPW; ++r)
        #pragma unroll
        for (int j = 0; j < 32; ++j)
            asm volatile("" : "+v"(w[r][j]));

    float bb = (lane < RPW) ? bhh[rbase + lane] : 0.f;
    float xv = (lane < RPW) ? xp[rbase + lane] : 0.f;

    const char* pbase = (const char*)pbuf;

    for (int t = 0; t < SEQ; ++t) {
        // prefetch next step's xp (hides under poll)
        float nx = 0.f;
        if (lane < RPW && t + 1 < SEQ) nx = xp[(size_t)(t + 1) * H + rbase + lane];

        const unsigned int e = (unsigned int)t;
        // buffer t&1, entry (4*lane + 256*k), 8 B/entry
        const char* p = pbase + ((t & 1) << 14) + (lane << 5);

        float4 qa0, qb0, qa1, qb1, qa2, qb2, qa3, qb3;
        float4 qa4, qb4, qa5, qb5, qa6, qb6, qa7, qb7;
        bool ok0 = false, ok1 = false, ok2 = false, ok3 = false;
        bool ok4 = false, ok5 = false, ok6 = false, ok7 = false;

        #define POLLC(k, qa, qb, ok)                                           \
            if (!ok) {                                                         \
                asm volatile("global_load_dwordx4 %0, %2, off sc0 sc1\n\t"    \
                             "global_load_dwordx4 %1, %2, off offset:16 sc0 sc1" \
                             : "=v"(qa), "=v"(qb)                              \
                             : "v"(p + ((k) << 11)));                          \
            }
        #define CHKC(qa, qb, ok)                                               \
            if (!ok) ok = __all(__float_as_uint(qa.y) == e &&                  \
                                __float_as_uint(qa.w) == e &&                  \
                                __float_as_uint(qb.y) == e &&                  \
                                __float_as_uint(qb.w) == e);

        for (;;) {
            POLLC(0, qa0, qb0, ok0) POLLC(1, qa1, qb1, ok1)
            POLLC(2, qa2, qb2, ok2) POLLC(3, qa3, qb3, ok3)
            POLLC(4, qa4, qb4, ok4) POLLC(5, qa5, qb5, ok5)
            POLLC(6, qa6, qb6, ok6) POLLC(7, qa7, qb7, ok7)
            asm volatile("s_waitcnt vmcnt(0)" ::: "memory");
            __builtin_amdgcn_sched_barrier(0);
            CHKC(qa0, qb0, ok0) CHKC(qa1, qb1, ok1)
            CHKC(qa2, qb2, ok2) CHKC(qa3, qb3, ok3)
            CHKC(qa4, qb4, ok4) CHKC(qa5, qb5, ok5)
            CHKC(qa6, qb6, ok6) CHKC(qa7, qb7, ok7)
            if (ok0 && ok1 && ok2 && ok3 && ok4 && ok5 && ok6 && ok7) break;
        }
        #undef POLLC
        #undef CHKC

        // --- GEMV: values live in .x/.z of the polled packets ---
        float a0 = 0.f, a1 = 0.f, a2 = 0.f, a3 = 0.f;
        #define GEMV4(k, qa, qb)                                               \
            a0 = fmaf(w[0][k*4+0], qa.x, a0); a0 = fmaf(w[0][k*4+1], qa.z, a0);\
            a0 = fmaf(w[0][k*4+2], qb.x, a0); a0 = fmaf(w[0][k*4+3], qb.z, a0);\
            a1 = fmaf(w[1][k*4+0], qa.x, a1); a1 = fmaf(w[1][k*4+1], qa.z, a1);\
            a1 = fmaf(w[1][k*4+2], qb.x, a1); a1 = fmaf(w[1][k*4+3], qb.z, a1);\
            a2 = fmaf(w[2][k*4+0], qa.x, a2); a2 = fmaf(w[2][k*4+1], qa.z, a2);\
            a2 = fmaf(w[2][k*4+2], qb.x, a2); a2 = fmaf(w[2][k*4+3], qb.z, a2);\
            a3 = fmaf(w[3][k*4+0], qa.x, a3); a3 = fmaf(w[3][k*4+1], qa.z, a3);\
            a3 = fmaf(w[3][k*4+2], qb.x, a3); a3 = fmaf(w[3][k*4+3], qb.z, a3);
        GEMV4(0, qa0, qb0) GEMV4(1, qa1, qb1) GEMV4(2, qa2, qb2) GEMV4(3, qa3, qb3)
        GEMV4(4, qa4, qb4) GEMV4(5, qa5, qb5) GEMV4(6, qa6, qb6) GEMV4(7, qa7, qb7)
        #undef GEMV4

        #pragma unroll
        for (int off = 32; off >= 1; off >>= 1) {
            a0 += __shfl_xor(a0, off);
            a1 += __shfl_xor(a1, off);
            a2 += __shfl_xor(a2, off);
            a3 += __shfl_xor(a3, off);
        }

        if (lane < RPW) {
            float av = (lane == 0) ? a0 : (lane == 1) ? a1 : (lane == 2) ? a2 : a3;
            float z  = av + xv + bb;
            // fast tanh: 2/(1+e^{-2z}) - 1  (v_exp + v_rcp, ~1e-6 abs err)
            float ex = __expf(-2.0f * z);
            float hval = __builtin_fmaf(2.0f, __builtin_amdgcn_rcpf(1.0f + ex), -1.0f);
            if (t + 1 < SEQ) {
                ulong64 pkt = ((ulong64)(unsigned int)(t + 1) << 32)
                            | (ulong64)__float_as_uint(hval);
                __hip_atomic_store(&pbuf[(((t + 1) & 1) << 11) + rbase + lane], pkt,
                                   __ATOMIC_RELAXED, __HIP_MEMORY_SCOPE_AGENT);
            }
            if (t >= SEQ - H)
                hs[(size_t)(t - (SEQ - H)) * H + rbase + lane] = hval;
        }
        xv = nx;
    }
}

// ---------------------------------------------------------------- launch
extern "C" void kernel_launch(void* const* d_in, const int* in_sizes, int n_in,
                              void* d_out, int out_size, void* d_ws, size_t ws_size,
                              hipStream_t stream) {
    const float* input  = (const float*)d_in[0];
    const float* hidden = (const float*)d_in[1];
    const float* W_ih   = (const float*)d_in[2];
    const float* b_ih   = (const float*)d_in[3];
    const float* W_hh   = (const float*)d_in[4];
    const float* b_hh   = (const float*)d_in[5];
    const float* W_out  = (const float*)d_in[6];
    const float* b_out  = (const float*)d_in[7];
    float* out = (float*)d_out;

    // ws layout: xp[SEQ*H] | hs[H*H] | pbuf[2*H packets of 8B]
    char* ws = (char*)d_ws;
    float*   xp   = (float*)ws;
    float*   hs   = (float*)(ws + (size_t)SEQ * H * 4);
    ulong64* pbuf = (ulong64*)(ws + (size_t)SEQ * H * 4 + (size_t)H * H * 4);

    init_kernel<<<dim3(8), dim3(256), 0, stream>>>(hidden, pbuf);

    // phase 1: xp = input @ W_ih^T + b_ih
    gemm_abt_f32<<<dim3(H / TS, SEQ / TS), dim3(256), 0, stream>>>(
        input, W_ih, b_ih, xp, SEQ, H, H);

    // phase 2: sequential scan, persistent weights, packet-polling exchange
    rnn_scan_kernel<<<dim3(NBLK), dim3(THREADS_REC), 0, stream>>>(
        xp, W_hh, b_hh, hs, pbuf);

    // phase 3: out = hs @ W_out^T + b_out
    gemm_abt_f32<<<dim3((NOUT + TS - 1) / TS, H / TS), dim3(256), 0, stream>>>(
        hs, W_out, b_out, out, H, NOUT, H);

    // output tuple tail: unchanged hidden state
    copy_hidden_kernel<<<dim3(8), dim3(256), 0, stream>>>(hidden, out + (size_t)H * NOUT);
}

// Round 11
// 10050.684 us; speedup vs baseline: 2.2067x; 2.2067x over previous
//
#include <hip/hip_runtime.h>
#include <math.h>

#define H 2048
#define SEQ 4096
#define NOUT 1000
#define NBLK 64          // recurrence blocks
#define RPB 32           // rows per block
#define RPW 4            // rows per wave
#define THREADS_REC 512  // 8 waves
#define FPAD 32          // flags padded to 128B (one LLC line each)

// ---------------------------------------------------------------- init
// buf0 <- h0 (so the scan always reads gbuf), flags <- 0
__global__ void init_kernel(const float* __restrict__ h0, float* __restrict__ gbuf,
                            int* __restrict__ flags) {
    int i = blockIdx.x * blockDim.x + threadIdx.x;
    if (i < H) gbuf[i] = h0[i];
    if (i < NBLK * FPAD) flags[i] = 0;
}

__global__ void copy_hidden_kernel(const float* __restrict__ hidden, float* __restrict__ out) {
    int i = blockIdx.x * blockDim.x + threadIdx.x;
    if (i < H) out[i] = hidden[i];
}

// ------------------------------------------- GEMM  C = A * Bt^T + bias
#define TS 64
#define KK 16
#define LP 21
__global__ __launch_bounds__(256) void gemm_abt_f32(
    const float* __restrict__ A, const float* __restrict__ Bt,
    const float* __restrict__ bias, float* __restrict__ C,
    int M, int N, int K)
{
    __shared__ float As[TS][LP];
    __shared__ float Bs[TS][LP];
    const int tid = threadIdx.x;
    const int tx = tid & 15, ty = tid >> 4;
    const int bm = blockIdx.y * TS, bn = blockIdx.x * TS;
    const int lrow = tid >> 2;
    const int lcol = (tid & 3) << 2;
    float acc[4][4] = {};
    for (int k0 = 0; k0 < K; k0 += KK) {
        float4 av, bv;
        av = *(const float4*)(A + (size_t)(bm + lrow) * K + k0 + lcol);
        int brow = bn + lrow;
        if (brow < N) bv = *(const float4*)(Bt + (size_t)brow * K + k0 + lcol);
        else { bv.x = bv.y = bv.z = bv.w = 0.f; }
        __syncthreads();
        As[lrow][lcol+0] = av.x; As[lrow][lcol+1] = av.y;
        As[lrow][lcol+2] = av.z; As[lrow][lcol+3] = av.w;
        Bs[lrow][lcol+0] = bv.x; Bs[lrow][lcol+1] = bv.y;
        Bs[lrow][lcol+2] = bv.z; Bs[lrow][lcol+3] = bv.w;
        __syncthreads();
        #pragma unroll
        for (int k = 0; k < KK; ++k) {
            float ar[4], br[4];
            #pragma unroll
            for (int i = 0; i < 4; ++i) ar[i] = As[ty*4+i][k];
            #pragma unroll
            for (int j = 0; j < 4; ++j) br[j] = Bs[tx*4+j][k];
            #pragma unroll
            for (int i = 0; i < 4; ++i)
                #pragma unroll
                for (int j = 0; j < 4; ++j)
                    acc[i][j] = fmaf(ar[i], br[j], acc[i][j]);
        }
    }
    #pragma unroll
    for (int i = 0; i < 4; ++i) {
        int row = bm + ty*4 + i;
        #pragma unroll
        for (int j = 0; j < 4; ++j) {
            int col = bn + tx*4 + j;
            if (col < N) C[(size_t)row * N + col] = acc[i][j] + bias[col];
        }
    }
}

// ------------------------------------------------- persistent RNN scan
// ROUND-5 PROVEN PROTOCOL (unchanged): 64 blocks x 512 threads; per step:
//   coherent dwordx4 loads of h_t -> GEMV regs, FMA+reduce+tanh,
//   relaxed agent store of slice -> LLC double buffer,
//   __syncthreads (drains all waves' slice stores), tid0 raises padded flag,
//   every wave polls all 64 padded flags (lane l watches flag l).
// Micro-opts this round: counted vmcnt(4)/vmcnt(0) GEMV split; fast tanh;
// hs (HBM) store moved after the flag so it overlaps the poll.
__global__ __launch_bounds__(THREADS_REC, 2) void rnn_scan_kernel(
    const float* __restrict__ xp, const float* __restrict__ Whh,
    const float* __restrict__ bhh,
    float* __restrict__ hs, float* gbuf, int* flags)
{
    const int tid  = threadIdx.x;
    const int lane = tid & 63;
    const int wid  = tid >> 6;
    const int bid  = blockIdx.x;
    const int rbase = bid * RPB + wid * RPW;

    // --- load weights into registers (one-time 16 MiB, coalesced) ---
    float w[RPW][32];
    #pragma unroll
    for (int r = 0; r < RPW; ++r) {
        const float* wp = Whh + (size_t)(rbase + r) * H + (lane << 2);
        #pragma unroll
        for (int k = 0; k < 8; ++k) {
            float4 wv = *(const float4*)(wp + (k << 8));
            w[r][k*4+0] = wv.x; w[r][k*4+1] = wv.y;
            w[r][k*4+2] = wv.z; w[r][k*4+3] = wv.w;
        }
    }
    #pragma unroll
    for (int r = 0; r < RPW; ++r)
        #pragma unroll
        for (int j = 0; j < 32; ++j)
            asm volatile("" : "+v"(w[r][j]));

    float bb = (lane < RPW) ? bhh[rbase + lane] : 0.f;
    float xv = (lane < RPW) ? xp[rbase + lane] : 0.f;

    for (int t = 0; t < SEQ; ++t) {
        // prefetch next step's xp (independent, hides under h loads)
        float nx = 0.f;
        if (lane < RPW && t + 1 < SEQ) nx = xp[(size_t)(t + 1) * H + rbase + lane];

        // --- coherent vector loads of h_t straight into GEMV registers ---
        const float* rb = gbuf + ((t & 1) << 11);
        const float* p  = rb + (lane << 2);
        float4 h0v, h1v, h2v, h3v, h4v, h5v, h6v, h7v;
        asm volatile("global_load_dwordx4 %0, %1, off sc0 sc1" : "=&v"(h0v) : "v"(p));
        asm volatile("global_load_dwordx4 %0, %1, off sc0 sc1" : "=&v"(h1v) : "v"(p + 256));
        asm volatile("global_load_dwordx4 %0, %1, off sc0 sc1" : "=&v"(h2v) : "v"(p + 512));
        asm volatile("global_load_dwordx4 %0, %1, off sc0 sc1" : "=&v"(h3v) : "v"(p + 768));
        asm volatile("global_load_dwordx4 %0, %1, off sc0 sc1" : "=&v"(h4v) : "v"(p + 1024));
        asm volatile("global_load_dwordx4 %0, %1, off sc0 sc1" : "=&v"(h5v) : "v"(p + 1280));
        asm volatile("global_load_dwordx4 %0, %1, off sc0 sc1" : "=&v"(h6v) : "v"(p + 1536));
        asm volatile("global_load_dwordx4 %0, %1, off sc0 sc1" : "=&v"(h7v) : "v"(p + 1792));

        float a0 = 0.f, a1 = 0.f, a2 = 0.f, a3 = 0.f;
        #define GEMV_STEP(k, hv)                                               \
            a0 = fmaf(w[0][k*4+0], hv.x, a0); a0 = fmaf(w[0][k*4+1], hv.y, a0);\
            a0 = fmaf(w[0][k*4+2], hv.z, a0); a0 = fmaf(w[0][k*4+3], hv.w, a0);\
            a1 = fmaf(w[1][k*4+0], hv.x, a1); a1 = fmaf(w[1][k*4+1], hv.y, a1);\
            a1 = fmaf(w[1][k*4+2], hv.z, a1); a1 = fmaf(w[1][k*4+3], hv.w, a1);\
            a2 = fmaf(w[2][k*4+0], hv.x, a2); a2 = fmaf(w[2][k*4+1], hv.y, a2);\
            a2 = fmaf(w[2][k*4+2], hv.z, a2); a2 = fmaf(w[2][k*4+3], hv.w, a2);\
            a3 = fmaf(w[3][k*4+0], hv.x, a3); a3 = fmaf(w[3][k*4+1], hv.y, a3);\
            a3 = fmaf(w[3][k*4+2], hv.z, a3); a3 = fmaf(w[3][k*4+3], hv.w, a3);

        // first 4 chunks are valid once at most 4 loads remain outstanding
        asm volatile("s_waitcnt vmcnt(4)" ::: "memory");
        __builtin_amdgcn_sched_barrier(0);
        GEMV_STEP(0, h0v) GEMV_STEP(1, h1v) GEMV_STEP(2, h2v) GEMV_STEP(3, h3v)
        asm volatile("s_waitcnt vmcnt(0)" ::: "memory");
        __builtin_amdgcn_sched_barrier(0);
        GEMV_STEP(4, h4v) GEMV_STEP(5, h5v) GEMV_STEP(6, h6v) GEMV_STEP(7, h7v)
        #undef GEMV_STEP

        #pragma unroll
        for (int off = 32; off >= 1; off >>= 1) {
            a0 += __shfl_xor(a0, off);
            a1 += __shfl_xor(a1, off);
            a2 += __shfl_xor(a2, off);
            a3 += __shfl_xor(a3, off);
        }

        float* wb = gbuf + (((t + 1) & 1) << 11);   // double buffer
        float hval = 0.f;
        if (lane < RPW) {
            float av = (lane == 0) ? a0 : (lane == 1) ? a1 : (lane == 2) ? a2 : a3;
            float z  = av + xv + bb;
            // fast tanh: 2/(1+e^{-2z}) - 1  (v_exp + v_rcp, ~1e-6 abs err)
            float ex = __expf(-2.0f * z);
            hval = __builtin_fmaf(2.0f, __builtin_amdgcn_rcpf(1.0f + ex), -1.0f);
            // direct-to-LLC store (sc1): coherent across XCDs
            __hip_atomic_store(&wb[rbase + lane], hval, __ATOMIC_RELAXED, __HIP_MEMORY_SCOPE_AGENT);
        }
        // drains every wave's vmcnt -> all 32 slice stores LLC-visible
        __syncthreads();

        if (tid == 0 && t + 1 < SEQ)
            __hip_atomic_store(&flags[bid * FPAD], t + 1, __ATOMIC_RELAXED, __HIP_MEMORY_SCOPE_AGENT);

        // hs (HBM) store off the critical path: overlaps the poll below
        if (lane < RPW && t >= SEQ - H)
            hs[(size_t)(t - (SEQ - H)) * H + rbase + lane] = hval;

        if (t + 1 < SEQ) {
            // every wave independently confirms all 64 flags (padded lines)
            for (;;) {
                int f = __hip_atomic_load(&flags[lane * FPAD], __ATOMIC_RELAXED, __HIP_MEMORY_SCOPE_AGENT);
                if (__all(f >= t + 1)) break;
            }
        }
        xv = nx;
    }
}

// ---------------------------------------------------------------- launch
extern "C" void kernel_launch(void* const* d_in, const int* in_sizes, int n_in,
                              void* d_out, int out_size, void* d_ws, size_t ws_size,
                              hipStream_t stream) {
    const float* input  = (const float*)d_in[0];
    const float* hidden = (const float*)d_in[1];
    const float* W_ih   = (const float*)d_in[2];
    const float* b_ih   = (const float*)d_in[3];
    const float* W_hh   = (const float*)d_in[4];
    const float* b_hh   = (const float*)d_in[5];
    const float* W_out  = (const float*)d_in[6];
    const float* b_out  = (const float*)d_in[7];
    float* out = (float*)d_out;

    // ws layout: xp[SEQ*H] | hs[H*H] | gbuf[2*H] | flags[NBLK*FPAD]
    char* ws = (char*)d_ws;
    float* xp    = (float*)ws;
    float* hs    = (float*)(ws + (size_t)SEQ * H * 4);
    float* gbuf  = (float*)(ws + (size_t)SEQ * H * 4 + (size_t)H * H * 4);
    int*   flags = (int*)  (ws + (size_t)SEQ * H * 4 + (size_t)H * H * 4 + 2 * H * 4);

    init_kernel<<<dim3(8), dim3(256), 0, stream>>>(hidden, gbuf, flags);

    // phase 1: xp = input @ W_ih^T + b_ih
    gemm_abt_f32<<<dim3(H / TS, SEQ / TS), dim3(256), 0, stream>>>(
        input, W_ih, b_ih, xp, SEQ, H, H);

    // phase 2: sequential scan, persistent weights
    rnn_scan_kernel<<<dim3(NBLK), dim3(THREADS_REC), 0, stream>>>(
        xp, W_hh, b_hh, hs, gbuf, flags);

    // phase 3: out = hs @ W_out^T + b_out
    gemm_abt_f32<<<dim3((NOUT + TS - 1) / TS, H / TS), dim3(256), 0, stream>>>(
        hs, W_out, b_out, out, H, NOUT, H);

    // output tuple tail: unchanged hidden state
    copy_hidden_kernel<<<dim3(8), dim3(256), 0, stream>>>(hidden, out + (size_t)H * NOUT);
}

// Round 13
// 10033.202 us; speedup vs baseline: 2.2105x; 1.0017x over previous
//
#include <hip/hip_runtime.h>
#include <math.h>

#define H 2048
#define SEQ 4096
#define NOUT 1000
#define NBLK 64          // recurrence blocks
#define RPB 32           // rows per block
#define RPW 4            // rows per wave
#define THREADS_REC 512  // 8 waves
#define FPAD 32          // flags padded to 128B (one LLC line each)

// ---------------------------------------------------------------- init
__global__ void init_kernel(const float* __restrict__ h0, float* __restrict__ gbuf,
                            int* __restrict__ flags) {
    int i = blockIdx.x * blockDim.x + threadIdx.x;
    if (i < H) gbuf[i] = h0[i];
    if (i < NBLK * FPAD) flags[i] = 0;
}

__global__ void copy_hidden_kernel(const float* __restrict__ hidden, float* __restrict__ out) {
    int i = blockIdx.x * blockDim.x + threadIdx.x;
    if (i < H) out[i] = hidden[i];
}

// ------------------------------------------- GEMM  C = A * Bt^T + bias
#define TS 64
#define KK 16
#define LP 21
__global__ __launch_bounds__(256) void gemm_abt_f32(
    const float* __restrict__ A, const float* __restrict__ Bt,
    const float* __restrict__ bias, float* __restrict__ C,
    int M, int N, int K)
{
    __shared__ float As[TS][LP];
    __shared__ float Bs[TS][LP];
    const int tid = threadIdx.x;
    const int tx = tid & 15, ty = tid >> 4;
    const int bm = blockIdx.y * TS, bn = blockIdx.x * TS;
    const int lrow = tid >> 2;
    const int lcol = (tid & 3) << 2;
    float acc[4][4] = {};
    for (int k0 = 0; k0 < K; k0 += KK) {
        float4 av, bv;
        av = *(const float4*)(A + (size_t)(bm + lrow) * K + k0 + lcol);
        int brow = bn + lrow;
        if (brow < N) bv = *(const float4*)(Bt + (size_t)brow * K + k0 + lcol);
        else { bv.x = bv.y = bv.z = bv.w = 0.f; }
        __syncthreads();
        As[lrow][lcol+0] = av.x; As[lrow][lcol+1] = av.y;
        As[lrow][lcol+2] = av.z; As[lrow][lcol+3] = av.w;
        Bs[lrow][lcol+0] = bv.x; Bs[lrow][lcol+1] = bv.y;
        Bs[lrow][lcol+2] = bv.z; Bs[lrow][lcol+3] = bv.w;
        __syncthreads();
        #pragma unroll
        for (int k = 0; k < KK; ++k) {
            float ar[4], br[4];
            #pragma unroll
            for (int i = 0; i < 4; ++i) ar[i] = As[ty*4+i][k];
            #pragma unroll
            for (int j = 0; j < 4; ++j) br[j] = Bs[tx*4+j][k];
            #pragma unroll
            for (int i = 0; i < 4; ++i)
                #pragma unroll
                for (int j = 0; j < 4; ++j)
                    acc[i][j] = fmaf(ar[i], br[j], acc[i][j]);
        }
    }
    #pragma unroll
    for (int i = 0; i < 4; ++i) {
        int row = bm + ty*4 + i;
        #pragma unroll
        for (int j = 0; j < 4; ++j) {
            int col = bn + tx*4 + j;
            if (col < N) C[(size_t)row * N + col] = acc[i][j] + bias[col];
        }
    }
}

// ------------------------------------------------- persistent RNN scan
// R11 PROVEN PROTOCOL, byte-for-byte: per step
//   coherent dwordx4 loads of h_t -> GEMV regs, FMA+reduce+fast-tanh,
//   relaxed agent store of slice -> LLC double buffer,
//   __syncthreads, tid0 raises padded flag, all waves poll 64 flags.
// This round's ONLY change: amdgpu_waves_per_eu(2,2) caps occupancy at
// exactly our real occupancy (8 waves/CU) so the allocator stops spilling
// the 128 weight floats (r11 showed VGPR=96 < 128 -> weights re-loaded
// every step on the serial path).
__global__ void __launch_bounds__(THREADS_REC)
__attribute__((amdgpu_waves_per_eu(2, 2)))
rnn_scan_kernel(
    const float* __restrict__ xp, const float* __restrict__ Whh,
    const float* __restrict__ bhh,
    float* __restrict__ hs, float* gbuf, int* flags)
{
    const int tid  = threadIdx.x;
    const int lane = tid & 63;
    const int wid  = tid >> 6;
    const int bid  = blockIdx.x;
    const int rbase = bid * RPB + wid * RPW;

    // --- load weights into registers (one-time 16 MiB, coalesced) ---
    float w[RPW][32];
    #pragma unroll
    for (int r = 0; r < RPW; ++r) {
        const float* wp = Whh + (size_t)(rbase + r) * H + (lane << 2);
        #pragma unroll
        for (int k = 0; k < 8; ++k) {
            float4 wv = *(const float4*)(wp + (k << 8));
            w[r][k*4+0] = wv.x; w[r][k*4+1] = wv.y;
            w[r][k*4+2] = wv.z; w[r][k*4+3] = wv.w;
        }
    }
    #pragma unroll
    for (int r = 0; r < RPW; ++r)
        #pragma unroll
        for (int j = 0; j < 32; ++j)
            asm volatile("" : "+v"(w[r][j]));

    float bb = (lane < RPW) ? bhh[rbase + lane] : 0.f;
    float xv = (lane < RPW) ? xp[rbase + lane] : 0.f;

    for (int t = 0; t < SEQ; ++t) {
        // prefetch next step's xp (independent, hides under h loads)
        float nx = 0.f;
        if (lane < RPW && t + 1 < SEQ) nx = xp[(size_t)(t + 1) * H + rbase + lane];

        // --- coherent vector loads of h_t straight into GEMV registers ---
        const float* rb = gbuf + ((t & 1) << 11);
        const float* p  = rb + (lane << 2);
        float4 h0v, h1v, h2v, h3v, h4v, h5v, h6v, h7v;
        asm volatile("global_load_dwordx4 %0, %1, off sc0 sc1" : "=&v"(h0v) : "v"(p));
        asm volatile("global_load_dwordx4 %0, %1, off sc0 sc1" : "=&v"(h1v) : "v"(p + 256));
        asm volatile("global_load_dwordx4 %0, %1, off sc0 sc1" : "=&v"(h2v) : "v"(p + 512));
        asm volatile("global_load_dwordx4 %0, %1, off sc0 sc1" : "=&v"(h3v) : "v"(p + 768));
        asm volatile("global_load_dwordx4 %0, %1, off sc0 sc1" : "=&v"(h4v) : "v"(p + 1024));
        asm volatile("global_load_dwordx4 %0, %1, off sc0 sc1" : "=&v"(h5v) : "v"(p + 1280));
        asm volatile("global_load_dwordx4 %0, %1, off sc0 sc1" : "=&v"(h6v) : "v"(p + 1536));
        asm volatile("global_load_dwordx4 %0, %1, off sc0 sc1" : "=&v"(h7v) : "v"(p + 1792));

        float a0 = 0.f, a1 = 0.f, a2 = 0.f, a3 = 0.f;
        #define GEMV_STEP(k, hv)                                               \
            a0 = fmaf(w[0][k*4+0], hv.x, a0); a0 = fmaf(w[0][k*4+1], hv.y, a0);\
            a0 = fmaf(w[0][k*4+2], hv.z, a0); a0 = fmaf(w[0][k*4+3], hv.w, a0);\
            a1 = fmaf(w[1][k*4+0], hv.x, a1); a1 = fmaf(w[1][k*4+1], hv.y, a1);\
            a1 = fmaf(w[1][k*4+2], hv.z, a1); a1 = fmaf(w[1][k*4+3], hv.w, a1);\
            a2 = fmaf(w[2][k*4+0], hv.x, a2); a2 = fmaf(w[2][k*4+1], hv.y, a2);\
            a2 = fmaf(w[2][k*4+2], hv.z, a2); a2 = fmaf(w[2][k*4+3], hv.w, a2);\
            a3 = fmaf(w[3][k*4+0], hv.x, a3); a3 = fmaf(w[3][k*4+1], hv.y, a3);\
            a3 = fmaf(w[3][k*4+2], hv.z, a3); a3 = fmaf(w[3][k*4+3], hv.w, a3);

        // first 4 chunks are valid once at most 4 loads remain outstanding
        asm volatile("s_waitcnt vmcnt(4)" ::: "memory");
        __builtin_amdgcn_sched_barrier(0);
        GEMV_STEP(0, h0v) GEMV_STEP(1, h1v) GEMV_STEP(2, h2v) GEMV_STEP(3, h3v)
        asm volatile("s_waitcnt vmcnt(0)" ::: "memory");
        __builtin_amdgcn_sched_barrier(0);
        GEMV_STEP(4, h4v) GEMV_STEP(5, h5v) GEMV_STEP(6, h6v) GEMV_STEP(7, h7v)
        #undef GEMV_STEP

        #pragma unroll
        for (int off = 32; off >= 1; off >>= 1) {
            a0 += __shfl_xor(a0, off);
            a1 += __shfl_xor(a1, off);
            a2 += __shfl_xor(a2, off);
            a3 += __shfl_xor(a3, off);
        }

        float* wb = gbuf + (((t + 1) & 1) << 11);   // double buffer
        float hval = 0.f;
        if (lane < RPW) {
            float av = (lane == 0) ? a0 : (lane == 1) ? a1 : (lane == 2) ? a2 : a3;
            float z  = av + xv + bb;
            // fast tanh: 2/(1+e^{-2z}) - 1  (v_exp + v_rcp, ~1e-6 abs err)
            float ex = __expf(-2.0f * z);
            hval = __builtin_fmaf(2.0f, __builtin_amdgcn_rcpf(1.0f + ex), -1.0f);
            // direct-to-LLC store (sc1): coherent across XCDs
            __hip_atomic_store(&wb[rbase + lane], hval, __ATOMIC_RELAXED, __HIP_MEMORY_SCOPE_AGENT);
        }
        // drains every wave's vmcnt -> all 32 slice stores LLC-visible
        __syncthreads();

        if (tid == 0 && t + 1 < SEQ)
            __hip_atomic_store(&flags[bid * FPAD], t + 1, __ATOMIC_RELAXED, __HIP_MEMORY_SCOPE_AGENT);

        // hs (HBM) store off the critical path: overlaps the poll below
        if (lane < RPW && t >= SEQ - H)
            hs[(size_t)(t - (SEQ - H)) * H + rbase + lane] = hval;

        if (t + 1 < SEQ) {
            // every wave independently confirms all 64 flags (padded lines)
            for (;;) {
                int f = __hip_atomic_load(&flags[lane * FPAD], __ATOMIC_RELAXED, __HIP_MEMORY_SCOPE_AGENT);
                if (__all(f >= t + 1)) break;
            }
        }
        xv = nx;
    }
}

// ---------------------------------------------------------------- launch
extern "C" void kernel_launch(void* const* d_in, const int* in_sizes, int n_in,
                              void* d_out, int out_size, void* d_ws, size_t ws_size,
                              hipStream_t stream) {
    const float* input  = (const float*)d_in[0];
    const float* hidden = (const float*)d_in[1];
    const float* W_ih   = (const float*)d_in[2];
    const float* b_ih   = (const float*)d_in[3];
    const float* W_hh   = (const float*)d_in[4];
    const float* b_hh   = (const float*)d_in[5];
    const float* W_out  = (const float*)d_in[6];
    const float* b_out  = (const float*)d_in[7];
    float* out = (float*)d_out;

    // ws layout: xp[SEQ*H] | hs[H*H] | gbuf[2*H] | flags[NBLK*FPAD]
    char* ws = (char*)d_ws;
    float* xp    = (float*)ws;
    float* hs    = (float*)(ws + (size_t)SEQ * H * 4);
    float* gbuf  = (float*)(ws + (size_t)SEQ * H * 4 + (size_t)H * H * 4);
    int*   flags = (int*)  (ws + (size_t)SEQ * H * 4 + (size_t)H * H * 4 + 2 * H * 4);

    init_kernel<<<dim3(8), dim3(256), 0, stream>>>(hidden, gbuf, flags);

    // phase 1: xp = input @ W_ih^T + b_ih
    gemm_abt_f32<<<dim3(H / TS, SEQ / TS), dim3(256), 0, stream>>>(
        input, W_ih, b_ih, xp, SEQ, H, H);

    // phase 2: sequential scan, persistent weights
    rnn_scan_kernel<<<dim3(NBLK), dim3(THREADS_REC), 0, stream>>>(
        xp, W_hh, b_hh, hs, gbuf, flags);

    // phase 3: out = hs @ W_out^T + b_out
    gemm_abt_f32<<<dim3((NOUT + TS - 1) / TS, H / TS), dim3(256), 0, stream>>>(
        hs, W_out, b_out, out, H, NOUT, H);

    // output tuple tail: unchanged hidden state
    copy_hidden_kernel<<<dim3(8), dim3(256), 0, stream>>>(hidden, out + (size_t)H * NOUT);
}

// Round 15
// 9689.371 us; speedup vs baseline: 2.2890x; 1.0355x over previous
//
#include <hip/hip_runtime.h>
#include <math.h>

#define H 2048
#define SEQ 4096
#define NOUT 1000
#define NBLK 64          // recurrence blocks
#define RPB 32           // rows per block
#define RPW 4            // rows per wave
#define THREADS_REC 512  // 8 waves
#define FPAD 32          // flags padded to 128B (one LLC line each)

// ---------------------------------------------------------------- init
__global__ void init_kernel(const float* __restrict__ h0, float* __restrict__ gbuf,
                            int* __restrict__ flags) {
    int i = blockIdx.x * blockDim.x + threadIdx.x;
    if (i < H) gbuf[i] = h0[i];
    if (i < NBLK * FPAD) flags[i] = 0;
}

__global__ void copy_hidden_kernel(const float* __restrict__ hidden, float* __restrict__ out) {
    int i = blockIdx.x * blockDim.x + threadIdx.x;
    if (i < H) out[i] = hidden[i];
}

// ------------------------------------------- GEMM  C = A * Bt^T + bias
// small tile (bounds-checked) — used for phase 3 (N=1000)
#define TS 64
#define KK 16
#define LP 21
__global__ __launch_bounds__(256) void gemm_abt_f32(
    const float* __restrict__ A, const float* __restrict__ Bt,
    const float* __restrict__ bias, float* __restrict__ C,
    int M, int N, int K)
{
    __shared__ float As[TS][LP];
    __shared__ float Bs[TS][LP];
    const int tid = threadIdx.x;
    const int tx = tid & 15, ty = tid >> 4;
    const int bm = blockIdx.y * TS, bn = blockIdx.x * TS;
    const int lrow = tid >> 2;
    const int lcol = (tid & 3) << 2;
    float acc[4][4] = {};
    for (int k0 = 0; k0 < K; k0 += KK) {
        float4 av, bv;
        av = *(const float4*)(A + (size_t)(bm + lrow) * K + k0 + lcol);
        int brow = bn + lrow;
        if (brow < N) bv = *(const float4*)(Bt + (size_t)brow * K + k0 + lcol);
        else { bv.x = bv.y = bv.z = bv.w = 0.f; }
        __syncthreads();
        As[lrow][lcol+0] = av.x; As[lrow][lcol+1] = av.y;
        As[lrow][lcol+2] = av.z; As[lrow][lcol+3] = av.w;
        Bs[lrow][lcol+0] = bv.x; Bs[lrow][lcol+1] = bv.y;
        Bs[lrow][lcol+2] = bv.z; Bs[lrow][lcol+3] = bv.w;
        __syncthreads();
        #pragma unroll
        for (int k = 0; k < KK; ++k) {
            float ar[4], br[4];
            #pragma unroll
            for (int i = 0; i < 4; ++i) ar[i] = As[ty*4+i][k];
            #pragma unroll
            for (int j = 0; j < 4; ++j) br[j] = Bs[tx*4+j][k];
            #pragma unroll
            for (int i = 0; i < 4; ++i)
                #pragma unroll
                for (int j = 0; j < 4; ++j)
                    acc[i][j] = fmaf(ar[i], br[j], acc[i][j]);
        }
    }
    #pragma unroll
    for (int i = 0; i < 4; ++i) {
        int row = bm + ty*4 + i;
        #pragma unroll
        for (int j = 0; j < 4; ++j) {
            int col = bn + tx*4 + j;
            if (col < N) C[(size_t)row * N + col] = acc[i][j] + bias[col];
        }
    }
}

// ----------------------- big-tile GEMM (no bounds; M%128==N%128==0, K%16==0)
// 128x128 tile, 256 threads, 8x8 microtile, K-transposed LDS (+4 pad).
#define BM 128
#define BN 128
#define BK 16
__global__ __launch_bounds__(256) void gemm_abt_f32_big(
    const float* __restrict__ A, const float* __restrict__ Bt,
    const float* __restrict__ bias, float* __restrict__ C,
    int M, int N, int K)
{
    __shared__ float As[BK][BM + 4];
    __shared__ float Bs[BK][BN + 4];
    const int tid = threadIdx.x;
    const int tx = tid & 15;          // n-group
    const int ty = tid >> 4;          // m-group
    const int bm = blockIdx.y * BM, bn = blockIdx.x * BN;
    const int lrow = tid >> 2;        // 0..63
    const int lcol = (tid & 3) << 2;  // 0,4,8,12
    float acc[8][8] = {};
    for (int k0 = 0; k0 < K; k0 += BK) {
        float4 a0 = *(const float4*)(A  + (size_t)(bm + lrow)      * K + k0 + lcol);
        float4 a1 = *(const float4*)(A  + (size_t)(bm + lrow + 64) * K + k0 + lcol);
        float4 b0 = *(const float4*)(Bt + (size_t)(bn + lrow)      * K + k0 + lcol);
        float4 b1 = *(const float4*)(Bt + (size_t)(bn + lrow + 64) * K + k0 + lcol);
        __syncthreads();
        As[lcol+0][lrow]      = a0.x; As[lcol+1][lrow]      = a0.y;
        As[lcol+2][lrow]      = a0.z; As[lcol+3][lrow]      = a0.w;
        As[lcol+0][lrow + 64] = a1.x; As[lcol+1][lrow + 64] = a1.y;
        As[lcol+2][lrow + 64] = a1.z; As[lcol+3][lrow + 64] = a1.w;
        Bs[lcol+0][lrow]      = b0.x; Bs[lcol+1][lrow]      = b0.y;
        Bs[lcol+2][lrow]      = b0.z; Bs[lcol+3][lrow]      = b0.w;
        Bs[lcol+0][lrow + 64] = b1.x; Bs[lcol+1][lrow + 64] = b1.y;
        Bs[lcol+2][lrow + 64] = b1.z; Bs[lcol+3][lrow + 64] = b1.w;
        __syncthreads();
        #pragma unroll
        for (int k = 0; k < BK; ++k) {
            float4 al = *(const float4*)&As[k][ty * 8];
            float4 ah = *(const float4*)&As[k][ty * 8 + 4];
            float4 bl = *(const float4*)&Bs[k][tx * 8];
            float4 bh = *(const float4*)&Bs[k][tx * 8 + 4];
            float ar[8] = {al.x, al.y, al.z, al.w, ah.x, ah.y, ah.z, ah.w};
            float br[8] = {bl.x, bl.y, bl.z, bl.w, bh.x, bh.y, bh.z, bh.w};
            #pragma unroll
            for (int i = 0; i < 8; ++i)
                #pragma unroll
                for (int j = 0; j < 8; ++j)
                    acc[i][j] = fmaf(ar[i], br[j], acc[i][j]);
        }
    }
    #pragma unroll
    for (int i = 0; i < 8; ++i) {
        float* crow = C + (size_t)(bm + ty * 8 + i) * N + bn + tx * 8;
        #pragma unroll
        for (int j = 0; j < 8; ++j)
            crow[j] = acc[i][j] + bias[bn + tx * 8 + j];
    }
}

// ------------------------------------------------- persistent RNN scan
// R11/R13 PROVEN STRUCTURE — BYTE-FOR-BYTE UNCHANGED. Do not restructure:
// r8/r9/r10/r12/r14 all failed correctness with any other exchange shape.
__global__ void __launch_bounds__(THREADS_REC)
__attribute__((amdgpu_waves_per_eu(2, 2)))
rnn_scan_kernel(
    const float* __restrict__ xp, const float* __restrict__ Whh,
    const float* __restrict__ bhh,
    float* __restrict__ hs, float* gbuf, int* flags)
{
    const int tid  = threadIdx.x;
    const int lane = tid & 63;
    const int wid  = tid >> 6;
    const int bid  = blockIdx.x;
    const int rbase = bid * RPB + wid * RPW;

    // --- load weights into registers (one-time 16 MiB, coalesced) ---
    float w[RPW][32];
    #pragma unroll
    for (int r = 0; r < RPW; ++r) {
        const float* wp = Whh + (size_t)(rbase + r) * H + (lane << 2);
        #pragma unroll
        for (int k = 0; k < 8; ++k) {
            float4 wv = *(const float4*)(wp + (k << 8));
            w[r][k*4+0] = wv.x; w[r][k*4+1] = wv.y;
            w[r][k*4+2] = wv.z; w[r][k*4+3] = wv.w;
        }
    }
    #pragma unroll
    for (int r = 0; r < RPW; ++r)
        #pragma unroll
        for (int j = 0; j < 32; ++j)
            asm volatile("" : "+v"(w[r][j]));

    float bb = (lane < RPW) ? bhh[rbase + lane] : 0.f;
    float xv = (lane < RPW) ? xp[rbase + lane] : 0.f;

    for (int t = 0; t < SEQ; ++t) {
        // prefetch next step's xp (independent, hides under h loads)
        float nx = 0.f;
        if (lane < RPW && t + 1 < SEQ) nx = xp[(size_t)(t + 1) * H + rbase + lane];

        // --- coherent vector loads of h_t straight into GEMV registers ---
        const float* rb = gbuf + ((t & 1) << 11);
        const float* p  = rb + (lane << 2);
        float4 h0v, h1v, h2v, h3v, h4v, h5v, h6v, h7v;
        asm volatile("global_load_dwordx4 %0, %1, off sc0 sc1" : "=&v"(h0v) : "v"(p));
        asm volatile("global_load_dwordx4 %0, %1, off sc0 sc1" : "=&v"(h1v) : "v"(p + 256));
        asm volatile("global_load_dwordx4 %0, %1, off sc0 sc1" : "=&v"(h2v) : "v"(p + 512));
        asm volatile("global_load_dwordx4 %0, %1, off sc0 sc1" : "=&v"(h3v) : "v"(p + 768));
        asm volatile("global_load_dwordx4 %0, %1, off sc0 sc1" : "=&v"(h4v) : "v"(p + 1024));
        asm volatile("global_load_dwordx4 %0, %1, off sc0 sc1" : "=&v"(h5v) : "v"(p + 1280));
        asm volatile("global_load_dwordx4 %0, %1, off sc0 sc1" : "=&v"(h6v) : "v"(p + 1536));
        asm volatile("global_load_dwordx4 %0, %1, off sc0 sc1" : "=&v"(h7v) : "v"(p + 1792));

        float a0 = 0.f, a1 = 0.f, a2 = 0.f, a3 = 0.f;
        #define GEMV_STEP(k, hv)                                               \
            a0 = fmaf(w[0][k*4+0], hv.x, a0); a0 = fmaf(w[0][k*4+1], hv.y, a0);\
            a0 = fmaf(w[0][k*4+2], hv.z, a0); a0 = fmaf(w[0][k*4+3], hv.w, a0);\
            a1 = fmaf(w[1][k*4+0], hv.x, a1); a1 = fmaf(w[1][k*4+1], hv.y, a1);\
            a1 = fmaf(w[1][k*4+2], hv.z, a1); a1 = fmaf(w[1][k*4+3], hv.w, a1);\
            a2 = fmaf(w[2][k*4+0], hv.x, a2); a2 = fmaf(w[2][k*4+1], hv.y, a2);\
            a2 = fmaf(w[2][k*4+2], hv.z, a2); a2 = fmaf(w[2][k*4+3], hv.w, a2);\
            a3 = fmaf(w[3][k*4+0], hv.x, a3); a3 = fmaf(w[3][k*4+1], hv.y, a3);\
            a3 = fmaf(w[3][k*4+2], hv.z, a3); a3 = fmaf(w[3][k*4+3], hv.w, a3);

        // first 4 chunks are valid once at most 4 loads remain outstanding
        asm volatile("s_waitcnt vmcnt(4)" ::: "memory");
        __builtin_amdgcn_sched_barrier(0);
        GEMV_STEP(0, h0v) GEMV_STEP(1, h1v) GEMV_STEP(2, h2v) GEMV_STEP(3, h3v)
        asm volatile("s_waitcnt vmcnt(0)" ::: "memory");
        __builtin_amdgcn_sched_barrier(0);
        GEMV_STEP(4, h4v) GEMV_STEP(5, h5v) GEMV_STEP(6, h6v) GEMV_STEP(7, h7v)
        #undef GEMV_STEP

        #pragma unroll
        for (int off = 32; off >= 1; off >>= 1) {
            a0 += __shfl_xor(a0, off);
            a1 += __shfl_xor(a1, off);
            a2 += __shfl_xor(a2, off);
            a3 += __shfl_xor(a3, off);
        }

        float* wb = gbuf + (((t + 1) & 1) << 11);   // double buffer
        float hval = 0.f;
        if (lane < RPW) {
            float av = (lane == 0) ? a0 : (lane == 1) ? a1 : (lane == 2) ? a2 : a3;
            float z  = av + xv + bb;
            // fast tanh: 2/(1+e^{-2z}) - 1  (v_exp + v_rcp, ~1e-6 abs err)
            float ex = __expf(-2.0f * z);
            hval = __builtin_fmaf(2.0f, __builtin_amdgcn_rcpf(1.0f + ex), -1.0f);
            // direct-to-LLC store (sc1): coherent across XCDs
            __hip_atomic_store(&wb[rbase + lane], hval, __ATOMIC_RELAXED, __HIP_MEMORY_SCOPE_AGENT);
        }
        // drains every wave's vmcnt -> all 32 slice stores LLC-visible
        __syncthreads();

        if (tid == 0 && t + 1 < SEQ)
            __hip_atomic_store(&flags[bid * FPAD], t + 1, __ATOMIC_RELAXED, __HIP_MEMORY_SCOPE_AGENT);

        // hs (HBM) store off the critical path: overlaps the poll below
        if (lane < RPW && t >= SEQ - H)
            hs[(size_t)(t - (SEQ - H)) * H + rbase + lane] = hval;

        if (t + 1 < SEQ) {
            // every wave independently confirms all 64 flags (padded lines)
            for (;;) {
                int f = __hip_atomic_load(&flags[lane * FPAD], __ATOMIC_RELAXED, __HIP_MEMORY_SCOPE_AGENT);
                if (__all(f >= t + 1)) break;
            }
        }
        xv = nx;
    }
}

// ---------------------------------------------------------------- launch
extern "C" void kernel_launch(void* const* d_in, const int* in_sizes, int n_in,
                              void* d_out, int out_size, void* d_ws, size_t ws_size,
                              hipStream_t stream) {
    const float* input  = (const float*)d_in[0];
    const float* hidden = (const float*)d_in[1];
    const float* W_ih   = (const float*)d_in[2];
    const float* b_ih   = (const float*)d_in[3];
    const float* W_hh   = (const float*)d_in[4];
    const float* b_hh   = (const float*)d_in[5];
    const float* W_out  = (const float*)d_in[6];
    const float* b_out  = (const float*)d_in[7];
    float* out = (float*)d_out;

    // ws layout: xp[SEQ*H] | hs[H*H] | gbuf[2*H] | flags[NBLK*FPAD]
    char* ws = (char*)d_ws;
    float* xp    = (float*)ws;
    float* hs    = (float*)(ws + (size_t)SEQ * H * 4);
    float* gbuf  = (float*)(ws + (size_t)SEQ * H * 4 + (size_t)H * H * 4);
    int*   flags = (int*)  (ws + (size_t)SEQ * H * 4 + (size_t)H * H * 4 + 2 * H * 4);

    init_kernel<<<dim3(8), dim3(256), 0, stream>>>(hidden, gbuf, flags);

    // phase 1: xp = input @ W_ih^T + b_ih   (4096x2048x2048 — all %128==0)
    gemm_abt_f32_big<<<dim3(H / BN, SEQ / BM), dim3(256), 0, stream>>>(
        input, W_ih, b_ih, xp, SEQ, H, H);

    // phase 2: sequential scan, persistent weights (UNCHANGED r11/r13)
    rnn_scan_kernel<<<dim3(NBLK), dim3(THREADS_REC), 0, stream>>>(
        xp, W_hh, b_hh, hs, gbuf, flags);

    // phase 3: out = hs @ W_out^T + b_out  (N=1000 -> bounds-checked tile)
    gemm_abt_f32<<<dim3((NOUT + TS - 1) / TS, H / TS), dim3(256), 0, stream>>>(
        hs, W_out, b_out, out, H, NOUT, H);

    // output tuple tail: unchanged hidden state
    copy_hidden_kernel<<<dim3(8), dim3(256), 0, stream>>>(hidden, out + (size_t)H * NOUT);
}